// Round 8
// baseline (3571.618 us; speedup 1.0000x reference)
//
#include <hip/hip_runtime.h>
#include <hip/hip_bf16.h>
#include <cstdint>
#include <cstddef>

#define BB 64
#define TT 512
#define II 1024
#define HH 1024
#define NSLOT 4

typedef __attribute__((ext_vector_type(8))) short bf16x8;
typedef __attribute__((ext_vector_type(4))) float f32x4;
typedef __attribute__((ext_vector_type(8))) ushort ushort8v;
typedef __attribute__((ext_vector_type(2))) unsigned long long u64x2;

// ---- ws layout (bytes) ----
#define OFF_WHH   0ull            // bf16 [4096][1024]
#define OFF_WIH   8388608ull      // bf16 [4096][1024]
#define OFF_BIAS  16777216ull     // f32 [4096]
#define OFF_HROT  16793600ull     // u32 [4][64][1024] rotating tagged exchange
#define OFF_HBUF  17842176ull     // bf16 [2][64][1024] (fallback)
#define OFF_CBUF  18104320ull     // f32 [64][1024]     (fallback)
#define OFF_PRE   18366464ull     // bf16 [512][64][4096]
#define OFF_XB_B  18366464ull     // bf16 [T][B][I] (fallback tier B)
#define NEED_A    286801920ull
#define NEED_B    85475328ull

__device__ __forceinline__ ushort f2b(float f) {
  union { float f; uint32_t u; } v; v.f = f;
  uint32_t r = v.u + 0x7fffu + ((v.u >> 16) & 1u);
  return (ushort)(r >> 16);
}
__device__ __forceinline__ float b2f(ushort u) {
  union { uint32_t u; float f; } v; v.u = ((uint32_t)u) << 16; return v.f;
}
__device__ __forceinline__ float sigm(float x) { return 1.0f / (1.0f + __expf(-x)); }
__device__ __forceinline__ float tanh_f(float x) {
  float e = __expf(2.0f * x);
  return 1.0f - 2.0f / (e + 1.0f);
}

// ---------- prep ----------
__global__ void k_prep(const float* __restrict__ wih, const float* __restrict__ whh,
                       const float* __restrict__ bih, const float* __restrict__ bhh,
                       const float* __restrict__ hx, const float* __restrict__ cx,
                       ushort* __restrict__ Whh_b, ushort* __restrict__ Wih_b,
                       float* __restrict__ bias, ushort* __restrict__ hbuf0,
                       float* __restrict__ cbuf, uint32_t* __restrict__ hrot) {
  const int tid = blockIdx.x * blockDim.x + threadIdx.x;
  const int nth = gridDim.x * blockDim.x;
  for (int idx = tid; idx < 4096 * 128; idx += nth) {   // chunks of 8
    const size_t o = (size_t)idx * 8;
    f32x4 h0 = *(const f32x4*)(whh + o), h1 = *(const f32x4*)(whh + o + 4);
    f32x4 i0 = *(const f32x4*)(wih + o), i1 = *(const f32x4*)(wih + o + 4);
    ushort8v a, b;
    a[0]=f2b(h0[0]); a[1]=f2b(h0[1]); a[2]=f2b(h0[2]); a[3]=f2b(h0[3]);
    a[4]=f2b(h1[0]); a[5]=f2b(h1[1]); a[6]=f2b(h1[2]); a[7]=f2b(h1[3]);
    b[0]=f2b(i0[0]); b[1]=f2b(i0[1]); b[2]=f2b(i0[2]); b[3]=f2b(i0[3]);
    b[4]=f2b(i1[0]); b[5]=f2b(i1[1]); b[6]=f2b(i1[2]); b[7]=f2b(i1[3]);
    *(ushort8v*)(Whh_b + o) = a;
    *(ushort8v*)(Wih_b + o) = b;
  }
  for (int idx = tid; idx < 4096; idx += nth) bias[idx] = bih[idx] + bhh[idx];
  for (int idx = tid; idx < BB * HH; idx += nth) {
    const ushort hb = f2b(hx[idx]);
    hbuf0[idx] = hb;
    cbuf[idx] = cx[idx];
    hrot[idx] = (uint32_t)hb;            // slot 0, tag t=0
  }
  // clear slots 1..3 tags (stale tags from a previous replay could alias)
  for (int idx = tid; idx < 3 * 65536; idx += nth)
    hrot[65536 + idx] = 0xFFFF0000u;
}

// ---------- x f32 [B][T][I] -> bf16 [T][B][I] (fallback tier) ----------
__global__ void k_convx_tb(const float* __restrict__ x, ushort* __restrict__ xb) {
  const int tid = blockIdx.x * blockDim.x + threadIdx.x;
  const int nth = gridDim.x * blockDim.x;
  for (int idx = tid; idx < TT * BB * (II / 8); idx += nth) {
    const int i8 = idx & 127;
    const int tb = idx >> 7;
    const int t = tb >> 6, b = tb & 63;
    const float* src = x + ((size_t)b * TT + t) * II + (size_t)i8 * 8;
    f32x4 v0 = *(const f32x4*)src, v1 = *(const f32x4*)(src + 4);
    ushort8v o;
    o[0]=f2b(v0[0]); o[1]=f2b(v0[1]); o[2]=f2b(v0[2]); o[3]=f2b(v0[3]);
    o[4]=f2b(v1[0]); o[5]=f2b(v1[1]); o[6]=f2b(v1[2]); o[7]=f2b(v1[3]);
    *(ushort8v*)(xb + (size_t)idx * 8) = o;
  }
}

// ---------- pre_x GEMM ([32768,1024] x [4096,1024]^T), inline f32->bf16 A ----------
template<bool FASTA>
__global__ void __launch_bounds__(256)
k_gemm(const ushort* __restrict__ xb, const float* __restrict__ xf,
       const ushort* __restrict__ Wih, ushort* __restrict__ pre) {
  __shared__ ushort As[2][8192];
  __shared__ ushort Bs[2][8192];
  const int tid = threadIdx.x;
  const int lane = tid & 63;
  const int w = tid >> 6;
  const int wm = w & 1, wn = w >> 1;
  const int l15 = lane & 15, kg = lane >> 4;
  const int work = (blockIdx.x & 7) * 1024 + (blockIdx.x >> 3);
  const int rp = work >> 5, cp = work & 31;
  const int m0 = rp * 128, n0 = cp * 128;

  f32x4 acc[4][4];
#pragma unroll
  for (int i = 0; i < 4; ++i)
#pragma unroll
    for (int j = 0; j < 4; ++j) acc[i][j] = f32x4{0.f, 0.f, 0.f, 0.f};

  bf16x8 ra[4], rb[4];

#define LOADTILE(KT)                                                          \
  {                                                                           \
    _Pragma("unroll")                                                         \
    for (int it = 0; it < 4; ++it) {                                          \
      const int idx = it * 256 + tid;                                         \
      const int row = idx >> 3, seg = idx & 7;                                \
      if (FASTA) {                                                            \
        ra[it] = *(const bf16x8*)(xb + (size_t)(m0 + row) * 1024 + (KT) * 64 + seg * 8); \
      } else {                                                                \
        const float* s = xf + (size_t)(m0 + row) * 1024 + (KT) * 64 + seg * 8;\
        f32x4 v0 = *(const f32x4*)s, v1 = *(const f32x4*)(s + 4);             \
        bf16x8 o;                                                             \
        o[0]=(short)f2b(v0[0]); o[1]=(short)f2b(v0[1]);                       \
        o[2]=(short)f2b(v0[2]); o[3]=(short)f2b(v0[3]);                       \
        o[4]=(short)f2b(v1[0]); o[5]=(short)f2b(v1[1]);                       \
        o[6]=(short)f2b(v1[2]); o[7]=(short)f2b(v1[3]);                       \
        ra[it] = o;                                                           \
      }                                                                       \
      rb[it] = *(const bf16x8*)(Wih + (size_t)(n0 + row) * 1024 + (KT) * 64 + seg * 8); \
    }                                                                         \
  }

#define WRITETILE(BUF)                                                        \
  {                                                                           \
    _Pragma("unroll")                                                         \
    for (int it = 0; it < 4; ++it) {                                          \
      const int idx = it * 256 + tid;                                         \
      const int row = idx >> 3, seg = idx & 7;                                \
      const int off = row * 64 + ((seg ^ (row & 7)) << 3);                    \
      *(bf16x8*)(&As[BUF][off]) = ra[it];                                     \
      *(bf16x8*)(&Bs[BUF][off]) = rb[it];                                     \
    }                                                                         \
  }

  LOADTILE(0);
  WRITETILE(0);
  __syncthreads();

#pragma unroll 1
  for (int kt = 0; kt < 16; ++kt) {
    const int cur = kt & 1;
    if (kt < 15) LOADTILE(kt + 1);
#pragma unroll
    for (int ks = 0; ks < 2; ++ks) {
      bf16x8 af[4], bf_[4];
      const int koff = ks * 32 + kg * 8;
      const int swz = koff ^ ((l15 & 7) << 3);
#pragma unroll
      for (int i = 0; i < 4; ++i) {
        const int arow = wm * 64 + i * 16 + l15;
        af[i] = *(const bf16x8*)(&As[cur][arow * 64 + swz]);
        const int brow = wn * 64 + i * 16 + l15;
        bf_[i] = *(const bf16x8*)(&Bs[cur][brow * 64 + swz]);
      }
#pragma unroll
      for (int i = 0; i < 4; ++i)
#pragma unroll
        for (int j = 0; j < 4; ++j)
          acc[i][j] = __builtin_amdgcn_mfma_f32_16x16x32_bf16(af[i], bf_[j], acc[i][j], 0, 0, 0);
    }
    if (kt < 15) WRITETILE(cur ^ 1);
    __syncthreads();
  }

#pragma unroll
  for (int i = 0; i < 4; ++i)
#pragma unroll
    for (int j = 0; j < 4; ++j)
#pragma unroll
      for (int e = 0; e < 4; ++e) {
        const int m = m0 + wm * 64 + i * 16 + kg * 4 + e;
        const int n = n0 + wn * 64 + j * 16 + l15;
        pre[((size_t)(m & 511) * 64 + (m >> 9)) * 4096 + n] = f2b(acc[i][j][e]);
      }
#undef LOADTILE
#undef WRITETILE
}

// ---------- persistent recurrence: XCD-local groups, flag-free tag-spin ----------
// 256 blocks x 512 thr (1/CU). Group g=bid&7 (8 batch rows) -> all 32 blocks of a
// group share one XCD (round-robin dispatch) => producer sc1 write-through updates
// the LOCAL L2; consumer plain loads hit it fresh. NSLOT=4 ring (L2-resident;
// overwrite-safe by data-dependency). No flag: per-wave tag-spin with selective
// agent-load retry (correct under ANY block->XCD mapping).
__global__ void __launch_bounds__(512, 2)
k_recur(const ushort* __restrict__ Whh_b, const float* __restrict__ bias,
        uint32_t* __restrict__ hrot, const ushort* __restrict__ pre,
        const float* __restrict__ cx,
        const float* __restrict__ wci, const float* __restrict__ wcf,
        const float* __restrict__ wco, float* __restrict__ out) {
  __shared__ float red[8][4][32][9];   // [wave][gate][h-local][row(8)+pad]
  const int tid = threadIdx.x;
  const int lane = tid & 63;
  const int w = tid >> 6;              // wave 0..7 -> K-slice [w*128, (w+1)*128)
  const int l15 = lane & 15, kg = lane >> 4;
  const int g = blockIdx.x & 7;        // XCD-local batch group: rows g*8..g*8+7
  const int j = blockIdx.x >> 3;       // h-slice j*32..j*32+31

  // W frags (B-operand): col = gate*1024 + j*32 + ct*16 + l15, k = w*128+ks*32+kg*8
  bf16x8 wf[4][2][4];
#pragma unroll
  for (int gt = 0; gt < 4; ++gt)
#pragma unroll
    for (int ct = 0; ct < 2; ++ct)
#pragma unroll
      for (int ks = 0; ks < 4; ++ks)
        wf[gt][ct][ks] = *(const bf16x8*)(Whh_b
            + (size_t)(gt * 1024 + j * 32 + ct * 16 + l15) * 1024
            + w * 128 + ks * 32 + kg * 8);

  // gate-thread role (tid < 256): row = tid&7, h-local = tid>>3 (0..31)
  const int grow = tid & 7;
  const int ghl = (tid >> 3) & 31;
  const int brow = g * 8 + grow;
  const int hidx = j * 32 + ghl;
  float bi = 0, bff = 0, bg = 0, bo = 0, pci = 0, pcf = 0, pco = 0, creg = 0;
  float pxi = 0, pxf = 0, pxg = 0, pxo = 0;
  if (tid < 256) {
    bi = bias[hidx]; bff = bias[1024 + hidx];
    bg = bias[2048 + hidx]; bo = bias[3072 + hidx];
    pci = wci[hidx]; pcf = wcf[hidx]; pco = wco[hidx];
    creg = cx[brow * 1024 + hidx];
    const ushort* pp0 = pre + ((size_t)brow) * 4096 + hidx;
    pxi = b2f(pp0[0]); pxf = b2f(pp0[1024]);
    pxg = b2f(pp0[2048]); pxo = b2f(pp0[3072]);
  }

  const int arow = g * 8 + (l15 & 7);  // A rows duplicated for l15 >= 8
  const unsigned long long MSK = 0xFFFF0000FFFF0000ULL;

#pragma unroll 1
  for (int t = 0; t < 512; ++t) {
    // prefetch pre[t+1] (independent of h; overlaps the tag-spin)
    ushort nx0 = 0, nx1 = 0, nx2 = 0, nx3 = 0;
    if (tid < 256) {
      const int tn = (t < 511) ? (t + 1) : 511;
      const ushort* pp = pre + ((size_t)tn * 64 + brow) * 4096 + hidx;
      nx0 = pp[0]; nx1 = pp[1024]; nx2 = pp[2048]; nx3 = pp[3072];
    }

    const unsigned long long* hq = (const unsigned long long*)
        (hrot + (size_t)(t & (NSLOT - 1)) * 65536 + (size_t)arow * 1024
         + w * 128 + kg * 8);
    const unsigned long long pat =
        ((unsigned long long)(uint32_t)t << 48) | ((unsigned long long)(uint32_t)t << 16);
    unsigned long long q[16];
#pragma unroll
    for (int ks = 0; ks < 4; ++ks) {   // plain 16B loads: local-L2 fast path
      u64x2 a = *(const u64x2*)(hq + ks * 16);
      u64x2 b = *(const u64x2*)(hq + ks * 16 + 2);
      q[ks * 4 + 0] = a[0]; q[ks * 4 + 1] = a[1];
      q[ks * 4 + 2] = b[0]; q[ks * 4 + 3] = b[1];
    }
    unsigned long long bad = 0;
#pragma unroll
    for (int qq = 0; qq < 16; ++qq) bad |= (q[qq] ^ pat) & MSK;
    int spins = 0;
    while (bad) {
      if (spins++ > 2) __builtin_amdgcn_s_sleep(1);
      // selective agent (MALL) reload of ONLY the not-yet-valid words
#pragma unroll
      for (int qq = 0; qq < 16; ++qq)
        if ((q[qq] ^ pat) & MSK)
          q[qq] = __hip_atomic_load(hq + (qq >> 2) * 16 + (qq & 3),
                                    __ATOMIC_RELAXED, __HIP_MEMORY_SCOPE_AGENT);
      bad = 0;
#pragma unroll
      for (int qq = 0; qq < 16; ++qq) bad |= (q[qq] ^ pat) & MSK;
    }

    f32x4 acc[4][2];
#pragma unroll
    for (int gt = 0; gt < 4; ++gt)
#pragma unroll
      for (int ct = 0; ct < 2; ++ct) acc[gt][ct] = f32x4{0.f, 0.f, 0.f, 0.f};
#pragma unroll
    for (int ks = 0; ks < 4; ++ks) {
      const unsigned long long v0 = q[ks * 4 + 0], v1 = q[ks * 4 + 1],
                               v2 = q[ks * 4 + 2], v3 = q[ks * 4 + 3];
      bf16x8 af;
      af[0] = (short)(v0 & 0xFFFF); af[1] = (short)((v0 >> 32) & 0xFFFF);
      af[2] = (short)(v1 & 0xFFFF); af[3] = (short)((v1 >> 32) & 0xFFFF);
      af[4] = (short)(v2 & 0xFFFF); af[5] = (short)((v2 >> 32) & 0xFFFF);
      af[6] = (short)(v3 & 0xFFFF); af[7] = (short)((v3 >> 32) & 0xFFFF);
#pragma unroll
      for (int gt = 0; gt < 4; ++gt)
#pragma unroll
        for (int ct = 0; ct < 2; ++ct)
          acc[gt][ct] = __builtin_amdgcn_mfma_f32_16x16x32_bf16(
              af, wf[gt][ct][ks], acc[gt][ct], 0, 0, 0);
    }

    // K-partials -> LDS (C/D: col=l15, row=kg*4+e; only rows 0..7 valid)
    if (kg < 2) {
#pragma unroll
      for (int gt = 0; gt < 4; ++gt)
#pragma unroll
        for (int ct = 0; ct < 2; ++ct)
#pragma unroll
          for (int e = 0; e < 4; ++e)
            red[w][gt][ct * 16 + l15][kg * 4 + e] = acc[gt][ct][e];
    }
    __syncthreads();

    if (tid < 256) {
      float s0 = 0.f, s1 = 0.f, s2 = 0.f, s3 = 0.f;
#pragma unroll
      for (int ww = 0; ww < 8; ++ww) {
        s0 += red[ww][0][ghl][grow];
        s1 += red[ww][1][ghl][grow];
        s2 += red[ww][2][ghl][grow];
        s3 += red[ww][3][ghl][grow];
      }
      const float ig = sigm(s0 + bi + pxi + pci * creg);
      const float fg = sigm(s1 + bff + pxf + pcf * creg);
      const float gg = tanh_f(s2 + bg + pxg);
      const float cy = fg * creg + ig * gg;
      const float og = sigm(s3 + bo + pxo + pco * cy);
      const float hy = og * tanh_f(cy);
      creg = cy;
      if (t < 511) {
        const uint32_t word = (((uint32_t)(t + 1)) << 16) | (uint32_t)f2b(hy);
        __hip_atomic_store(&hrot[(size_t)((t + 1) & (NSLOT - 1)) * 65536
                                 + brow * 1024 + hidx],
                           word, __ATOMIC_RELAXED, __HIP_MEMORY_SCOPE_AGENT);
      }
      __builtin_nontemporal_store(hy,
          &out[(size_t)brow * 524288 + (size_t)t * 1024 + hidx]);
      pxi = b2f(nx0); pxf = b2f(nx1); pxg = b2f(nx2); pxo = b2f(nx3);
    }
    __syncthreads();   // protect red[] before next step's writes
  }
}

// ---------- fallback: per-timestep kernel (known-pass) ----------
template<bool XB>
__global__ void __launch_bounds__(256)
k_step2(const ushort* __restrict__ Whh, const ushort* __restrict__ Wih,
        const float* __restrict__ bias,
        const ushort* __restrict__ hprev, ushort* __restrict__ hnext,
        float* __restrict__ cbuf, const ushort* __restrict__ xb,
        const float* __restrict__ x,
        const float* __restrict__ wci, const float* __restrict__ wcf,
        const float* __restrict__ wco, float* __restrict__ out, int t) {
  __shared__ float pre[32][33];
  const int lane = threadIdx.x & 63;
  const int w = threadIdx.x >> 6;
  const int mt = w & 1, ct = w >> 1;
  const int mg = blockIdx.x & 1, cg = blockIdx.x >> 1;
  const int l15 = lane & 15, kg = lane >> 4;
  const int arow = mg * 32 + mt * 16 + l15;
  const int gate = ct * 2 + (l15 >> 3);
  const int hl = l15 & 7;
  const int gcol = gate * HH + cg * 8 + hl;

  const ushort* wr = Whh + (size_t)gcol * 1024 + kg * 8;
  const ushort* hr = hprev + (size_t)arow * HH + kg * 8;

  f32x4 acc0 = {0.f,0.f,0.f,0.f};
  f32x4 acc1 = {0.f,0.f,0.f,0.f};

#pragma unroll 8
  for (int ks = 0; ks < 32; ks += 2) {
    bf16x8 a0 = *(const bf16x8*)(hr + ks * 32);
    bf16x8 b0 = *(const bf16x8*)(wr + ks * 32);
    acc0 = __builtin_amdgcn_mfma_f32_16x16x32_bf16(a0, b0, acc0, 0, 0, 0);
    bf16x8 a1 = *(const bf16x8*)(hr + ks * 32 + 32);
    bf16x8 b1 = *(const bf16x8*)(wr + ks * 32 + 32);
    acc1 = __builtin_amdgcn_mfma_f32_16x16x32_bf16(a1, b1, acc1, 0, 0, 0);
  }
  const ushort* wrx = Wih + (size_t)gcol * 1024 + kg * 8;
  if (XB) {
    const ushort* xr = xb + ((size_t)t * BB + arow) * II + kg * 8;
#pragma unroll 8
    for (int ks = 0; ks < 32; ks += 2) {
      bf16x8 a0 = *(const bf16x8*)(xr + ks * 32);
      bf16x8 b0 = *(const bf16x8*)(wrx + ks * 32);
      acc0 = __builtin_amdgcn_mfma_f32_16x16x32_bf16(a0, b0, acc0, 0, 0, 0);
      bf16x8 a1 = *(const bf16x8*)(xr + ks * 32 + 32);
      bf16x8 b1 = *(const bf16x8*)(wrx + ks * 32 + 32);
      acc1 = __builtin_amdgcn_mfma_f32_16x16x32_bf16(a1, b1, acc1, 0, 0, 0);
    }
  } else {
    const float* xr = x + ((size_t)arow * TT + t) * II + kg * 8;
#pragma unroll 4
    for (int ks = 0; ks < 32; ++ks) {
      f32x4 v0 = *(const f32x4*)(xr + ks * 32);
      f32x4 v1 = *(const f32x4*)(xr + ks * 32 + 4);
      bf16x8 a;
      a[0]=(short)f2b(v0[0]); a[1]=(short)f2b(v0[1]);
      a[2]=(short)f2b(v0[2]); a[3]=(short)f2b(v0[3]);
      a[4]=(short)f2b(v1[0]); a[5]=(short)f2b(v1[1]);
      a[6]=(short)f2b(v1[2]); a[7]=(short)f2b(v1[3]);
      bf16x8 b0 = *(const bf16x8*)(wrx + ks * 32);
      acc0 = __builtin_amdgcn_mfma_f32_16x16x32_bf16(a, b0, acc0, 0, 0, 0);
    }
  }
  f32x4 acc = acc0 + acc1;

  const float bv = bias[gcol];
  const int lr0 = mt * 16 + kg * 4;
  const int lc2 = ct * 16 + l15;
#pragma unroll
  for (int jj = 0; jj < 4; ++jj) pre[lr0 + jj][lc2] = acc[jj] + bv;
  __syncthreads();

  const int tid = threadIdx.x;
  const int lr = tid >> 3;
  const int hl2 = tid & 7;
  const int b = mg * 32 + lr;
  const int hi = cg * 8 + hl2;
  const float ip = pre[lr][hl2];
  const float fp = pre[lr][8 + hl2];
  const float gp = pre[lr][16 + hl2];
  const float op = pre[lr][24 + hl2];
  const float c = cbuf[b * HH + hi];
  const float ig = sigm(ip + wci[hi] * c);
  const float fg = sigm(fp + wcf[hi] * c);
  const float gg = tanh_f(gp);
  const float cy = fg * c + ig * gg;
  const float og = sigm(op + wco[hi] * cy);
  const float hy = og * tanh_f(cy);
  cbuf[b * HH + hi] = cy;
  hnext[b * HH + hi] = f2b(hy);
  out[((size_t)b * TT + t) * HH + hi] = hy;
}

extern "C" void kernel_launch(void* const* d_in, const int* in_sizes, int n_in,
                              void* d_out, int out_size, void* d_ws, size_t ws_size,
                              hipStream_t stream) {
  const float* x   = (const float*)d_in[0];
  const float* hx  = (const float*)d_in[1];
  const float* cx  = (const float*)d_in[2];
  const float* wih = (const float*)d_in[3];
  const float* whh = (const float*)d_in[4];
  const float* bih = (const float*)d_in[5];
  const float* bhh = (const float*)d_in[6];
  const float* wci = (const float*)d_in[7];
  const float* wcf = (const float*)d_in[8];
  const float* wco = (const float*)d_in[9];
  float* out = (float*)d_out;

  char* ws = (char*)d_ws;
  ushort*   Whh_b = (ushort*)(ws + OFF_WHH);
  ushort*   Wih_b = (ushort*)(ws + OFF_WIH);
  float*    bias  = (float*)(ws + OFF_BIAS);
  uint32_t* hrot  = (uint32_t*)(ws + OFF_HROT);
  ushort*   hbuf  = (ushort*)(ws + OFF_HBUF);
  float*    cbuf  = (float*)(ws + OFF_CBUF);
  ushort*   pre   = (ushort*)(ws + OFF_PRE);

  k_prep<<<512, 256, 0, stream>>>(wih, whh, bih, bhh, hx, cx,
                                  Whh_b, Wih_b, bias, hbuf, cbuf, hrot);

  if (ws_size >= NEED_A) {
    k_gemm<false><<<8192, 256, 0, stream>>>(nullptr, x, Wih_b, pre);
    k_recur<<<256, 512, 0, stream>>>(Whh_b, bias, hrot, pre, cx,
                                     wci, wcf, wco, out);
  } else if (ws_size >= NEED_B) {
    ushort* xb = (ushort*)(ws + OFF_XB_B);
    k_convx_tb<<<1024, 256, 0, stream>>>(x, xb);
    for (int t = 0; t < TT; ++t) {
      const ushort* hp = hbuf + (size_t)(t & 1) * BB * HH;
      ushort* hn = hbuf + (size_t)((t + 1) & 1) * BB * HH;
      k_step2<true><<<256, 256, 0, stream>>>(Whh_b, Wih_b, bias, hp, hn, cbuf,
                                             xb, x, wci, wcf, wco, out, t);
    }
  } else {
    for (int t = 0; t < TT; ++t) {
      const ushort* hp = hbuf + (size_t)(t & 1) * BB * HH;
      ushort* hn = hbuf + (size_t)((t + 1) & 1) * BB * HH;
      k_step2<false><<<256, 256, 0, stream>>>(Whh_b, Wih_b, bias, hp, hn, cbuf,
                                              nullptr, x, wci, wcf, wco, out, t);
    }
  }

  // state outputs = INITIAL (hx, cx), per reference
  hipMemcpyAsync(out + 33554432, hx, (size_t)BB * HH * 4,
                 hipMemcpyDeviceToDevice, stream);
  hipMemcpyAsync(out + 33554432 + 65536, cx, (size_t)BB * HH * 4,
                 hipMemcpyDeviceToDevice, stream);
}